// Round 6
// baseline (784.286 us; speedup 1.0000x reference)
//
#include <hip/hip_runtime.h>
#include <hip/hip_bf16.h>
#include <math.h>

typedef unsigned short u16;
typedef unsigned int   u32;
typedef short v8s __attribute__((ext_vector_type(8)));
typedef float v4f __attribute__((ext_vector_type(4)));
#define DEV static __device__ __forceinline__

DEV float u2f(u16 u){ union{u32 i; float f;} v; v.i = ((u32)u)<<16; return v.f; }
DEV u16   f2u(float f){ union{float ff; u32 i;} v; v.ff = f; u32 r = v.i + 0x7fffu + ((v.i>>16)&1u); return (u16)(r>>16); }
DEV float lrelu02(float x){ return x > 0.f ? x : 0.2f*x; }
DEV float lrelu01(float x){ return x > 0.f ? x : 0.01f*x; }
DEV float wred_max(float v){
  #pragma unroll
  for (int o = 32; o > 0; o >>= 1) v = fmaxf(v, __shfl_xor(v, o, 64));
  return v;
}
DEV float wred_sum(float v){
  #pragma unroll
  for (int o = 32; o > 0; o >>= 1) v += __shfl_xor(v, o, 64);
  return v;
}
// packed u32 = two bf16 (lo = even col, hi = odd col)
DEV void acc2(float w, u32 pk, float& a0, float& a1){
  union{u32 i; float f;} lo, hi;
  lo.i = pk << 16; hi.i = pk & 0xffff0000u;
  a0 = fmaf(w, lo.f, a0); a1 = fmaf(w, hi.f, a1);
}

constexpr int B_   = 8;
constexpr int P_   = 32;
constexpr int N0_  = 10000;
constexpr int NODES = B_ * N0_;      // 80000
constexpr int E_   = 160000;
constexpr int NE_  = E_ + N0_;       // 170000

// ---------------- utility ----------------
__global__ void k_zero(int* __restrict__ p, int n){
  int i = blockIdx.x*blockDim.x + threadIdx.x;
  if (i < n) p[i] = 0;
}

// weight transpose+cast: dst[n][k] (bf16, padded) from src[k][n] (f32)
__global__ void k_wt(u16* __restrict__ dst, const float* __restrict__ src,
                     int NR, int NKp, int Nsrc, int Klim, int mode){
  int i = blockIdx.x*blockDim.x + threadIdx.x;
  if (i >= NR*NKp) return;
  int n = i / NKp, k = i - n*NKp;
  float v = 0.f;
  if (n < Nsrc){
    if (mode == 0){ if (k < Klim) v = src[(size_t)k*Nsrc + n]; }
    else {
      if (k < 136) v = src[(size_t)k*Nsrc + n];
      else if (k >= 160 && k < 296) v = src[(size_t)(k-24)*Nsrc + n];
    }
  }
  dst[i] = f2u(v);
}

// ---------------- backbone ----------------
DEV void load_convw(float* lw, const float* wl1, const float* wl2, const float* wp1,
                    const float* wp2, const float* wg, int tid, int nth){
  for (int i = tid; i < 384; i += nth){
    float v;
    if      (i < 24)  v = wl1[i];
    else if (i < 64)  v = wl2[i-24];
    else if (i < 88)  v = wp1[i-64];
    else if (i < 128) v = wp2[i-88];
    else              v = wg [i-128];
    lw[i] = v;
  }
}

template<int KS,int DIL,int T>
DEV void conv_stats(const float* xc, const float* wk, float& s, float& q){
  #pragma unroll
  for (int t = 0; t < T; t++){
    float v = 0.f;
    #pragma unroll
    for (int j = 0; j < KS; j++) v = fmaf(wk[j], xc[t + j*DIL], v);
    s += v; q = fmaf(v, v, q);
  }
}

__global__ void __launch_bounds__(256) k_bn_stats(
    const float* __restrict__ x,
    const float* __restrict__ wl1, const float* __restrict__ wl2,
    const float* __restrict__ wp1, const float* __restrict__ wp2,
    const float* __restrict__ wg,
    float* __restrict__ gsum, float* __restrict__ gsq)
{
  __shared__ float lw[384];
  __shared__ float lacc[80];
  const int tid = threadIdx.x;
  load_convw(lw, wl1, wl2, wp1, wp2, wg, tid, 256);
  if (tid < 80) lacc[tid] = 0.f;
  __syncthreads();

  int gid = blockIdx.x*256 + tid;
  float xc[P_];
  if (gid < NODES){
    int b = gid / N0_, n = gid - b*N0_;
    const float* xp = x + (size_t)b*P_*N0_ + n;
    #pragma unroll
    for (int p = 0; p < P_; p++) xc[p] = xp[(size_t)p*N0_];
  } else {
    #pragma unroll
    for (int p = 0; p < P_; p++) xc[p] = 0.f;
  }
  const int lane = tid & 63;

  auto red = [&](int ch, float s, float q){
    #pragma unroll
    for (int o = 32; o > 0; o >>= 1){ s += __shfl_down(s,o,64); q += __shfl_down(q,o,64); }
    if (lane == 0){ atomicAdd(&lacc[ch], s); atomicAdd(&lacc[40+ch], q); }
  };

  #pragma unroll
  for (int k = 0; k < 8; k++){ float s=0,q=0; conv_stats<3,1,30>(xc, lw      + k*3 , s,q); red(k,     s,q); }
  #pragma unroll
  for (int k = 0; k < 8; k++){ float s=0,q=0; conv_stats<5,1,28>(xc, lw + 24 + k*5 , s,q); red(8+k,   s,q); }
  #pragma unroll
  for (int k = 0; k < 8; k++){ float s=0,q=0; conv_stats<3,2,28>(xc, lw + 64 + k*3 , s,q); red(16+k,  s,q); }
  #pragma unroll
  for (int k = 0; k < 8; k++){ float s=0,q=0; conv_stats<5,2,24>(xc, lw + 88 + k*5 , s,q); red(24+k,  s,q); }
  #pragma unroll
  for (int k = 0; k < 8; k++){ float s=0,q=0; conv_stats<32,1,1>(xc, lw + 128+ k*32, s,q); red(32+k,  s,q); }

  __syncthreads();
  if (tid < 40)      atomicAdd(&gsum[tid],    lacc[tid]);
  else if (tid < 80) atomicAdd(&gsq [tid-40], lacc[tid]);
}

__global__ void k_bn_fin(const float* __restrict__ gsum, const float* __restrict__ gsq,
                         float* __restrict__ sA, float* __restrict__ sB,
                         const float* g0, const float* g1, const float* g2, const float* g3, const float* g4,
                         const float* e0, const float* e1, const float* e2, const float* e3, const float* e4)
{
  int t = threadIdx.x;
  if (t >= 40) return;
  int bi = t >> 3, k = t & 7;
  const int Ts[5] = {30,28,28,24,1};
  float cnt  = (float)NODES * (float)Ts[bi];
  float mean = gsum[t] / cnt;
  float var  = gsq[t] / cnt - mean*mean;
  const float* gp = bi==0?g0: bi==1?g1: bi==2?g2: bi==3?g3: g4;
  const float* ep = bi==0?e0: bi==1?e1: bi==2?e2: bi==3?e3: e4;
  float a = gp[k] * rsqrtf(fmaxf(var, 0.f) + 1e-5f);
  sA[t] = a;
  sB[t] = ep[k] - a*mean;
}

template<int KS,int DIL,int T>
DEV void conv_pool4(const float* xc, const float* wk, float A, float Bc, float* o4){
  float y[T];
  #pragma unroll
  for (int t = 0; t < T; t++){
    float v = 0.f;
    #pragma unroll
    for (int j = 0; j < KS; j++) v = fmaf(wk[j], xc[t + j*DIL], v);
    y[t] = fmaf(A, v, Bc);
  }
  #pragma unroll
  for (int i = 0; i < 4; i++){
    const int lo = (i*T)/4, hi = ((i+1)*T + 3)/4;
    float m = y[lo];
    #pragma unroll
    for (int t = 0; t < T; t++){ if (t > lo && t < hi) m = fmaxf(m, y[t]); }
    o4[i] = m;
  }
}

// writes feat row-major [m][160] bf16 (tanh applied)
__global__ void __launch_bounds__(256) k_feat(
    const float* __restrict__ x,
    const float* __restrict__ wl1, const float* __restrict__ wl2,
    const float* __restrict__ wp1, const float* __restrict__ wp2,
    const float* __restrict__ wg,
    const float* __restrict__ sA, const float* __restrict__ sB,
    u16* __restrict__ feat, int base, int m)
{
  __shared__ float lw[384];
  __shared__ float lA[40], lB[40];
  const int tid = threadIdx.x;
  load_convw(lw, wl1, wl2, wp1, wp2, wg, tid, 256);
  if (tid < 40){ lA[tid] = sA[tid]; lB[tid] = sB[tid]; }
  __syncthreads();

  int gid = blockIdx.x*256 + tid;
  if (gid >= m) return;
  int g = base + gid;
  int b = g / N0_, n = g - b*N0_;
  float xc[P_];
  const float* xp = x + (size_t)b*P_*N0_ + n;
  #pragma unroll
  for (int p = 0; p < P_; p++) xc[p] = xp[(size_t)p*N0_];

  u32 pk[4];
  u16* orow = feat + (size_t)gid*160;
  auto emit = [&](int ch, float v){
    u16 h = f2u(tanhf(v));
    int s = ch & 7;
    if ((s & 1) == 0) pk[s>>1] = h;
    else              pk[s>>1] |= ((u32)h) << 16;
    if (s == 7) *(uint4*)(orow + (ch - 7)) = make_uint4(pk[0],pk[1],pk[2],pk[3]);
  };

  float o4[4];
  #pragma unroll
  for (int k = 0; k < 8; k++){
    conv_pool4<3,1,30>(xc, lw + k*3, lA[k], lB[k], o4);
    #pragma unroll
    for (int i = 0; i < 4; i++) emit(k*4+i, o4[i]);
  }
  #pragma unroll
  for (int k = 0; k < 8; k++){
    conv_pool4<5,1,28>(xc, lw + 24 + k*5, lA[8+k], lB[8+k], o4);
    #pragma unroll
    for (int i = 0; i < 4; i++) emit(32 + k*4+i, o4[i]);
  }
  #pragma unroll
  for (int k = 0; k < 8; k++){
    conv_pool4<3,2,28>(xc, lw + 64 + k*3, lA[16+k], lB[16+k], o4);
    #pragma unroll
    for (int i = 0; i < 4; i++) emit(64 + k*4+i, o4[i]);
  }
  #pragma unroll
  for (int k = 0; k < 8; k++){
    conv_pool4<5,2,24>(xc, lw + 88 + k*5, lA[24+k], lB[24+k], o4);
    #pragma unroll
    for (int i = 0; i < 4; i++) emit(96 + k*4+i, o4[i]);
  }
  #pragma unroll
  for (int k = 0; k < 8; k++){
    float v = 0.f;
    #pragma unroll
    for (int j = 0; j < 32; j++) v = fmaf(lw[128 + k*32 + j], xc[j], v);
    emit(128 + k, fmaf(lA[32+k], v, lB[32+k]));
  }
}

// ---------------- CSR ----------------
__global__ void k_count(const int* __restrict__ ei, int* __restrict__ counts){
  int e = blockIdx.x*blockDim.x + threadIdx.x;
  if (e >= NE_) return;
  int dst = (e < E_) ? ei[E_ + e] : (e - E_);
  atomicAdd(&counts[dst], 1);
}

__global__ void __launch_bounds__(1024) k_scan(const int* __restrict__ counts, int* __restrict__ offs){
  __shared__ int part[1024];
  int t = threadIdx.x;
  int loc[10]; int s = 0;
  #pragma unroll
  for (int i = 0; i < 10; i++){
    int idx = t*10 + i;
    int c = (idx < N0_) ? counts[idx] : 0;
    loc[i] = s; s += c;
  }
  part[t] = s;
  __syncthreads();
  for (int o = 1; o < 1024; o <<= 1){
    int v = (t >= o) ? part[t-o] : 0;
    __syncthreads();
    part[t] += v;
    __syncthreads();
  }
  int pre = (t == 0) ? 0 : part[t-1];
  #pragma unroll
  for (int i = 0; i < 10; i++){
    int idx = t*10 + i;
    if (idx < N0_) offs[idx] = pre + loc[i];
  }
  if (t == 0) offs[N0_] = part[1023];
}

__global__ void k_scatter(const int* __restrict__ ei, const int* __restrict__ offs,
                          int* __restrict__ cursor, int* __restrict__ srcl){
  int e = blockIdx.x*blockDim.x + threadIdx.x;
  if (e >= NE_) return;
  int src, dst;
  if (e < E_){ src = ei[e]; dst = ei[E_ + e]; } else { src = dst = e - E_; }
  int pos = atomicAdd(&cursor[dst], 1);
  srcl[offs[dst] + pos] = src;
}

// ---------------- MFMA GEMM: A[m][K] bf16 row-major, BT[n][K] bf16, C[m][N] bf16 ----------------
template<int KT1,int KT2,int NT,int EPI>
__global__ void __launch_bounds__(256) k_mfma(
    const u16* __restrict__ A1, int sA1,
    const u16* __restrict__ A2, int sA2,
    const u16* __restrict__ BT, int sBT,
    u16* __restrict__ C, int sC, int nbase,
    const float* __restrict__ bias, int m)
{
  const int wv = threadIdx.x >> 6, lane = threadIdx.x & 63;
  const int quad = lane >> 4, l15 = lane & 15;
  const int mb = blockIdx.x*256 + wv*64;
  int ar[4];
  #pragma unroll
  for (int mt = 0; mt < 4; mt++) ar[mt] = min(mb + mt*16 + l15, m-1);

  v4f acc[4][NT];
  #pragma unroll
  for (int mt = 0; mt < 4; mt++)
    #pragma unroll
    for (int nt = 0; nt < NT; nt++)
      acc[mt][nt] = (v4f){0.f,0.f,0.f,0.f};

  for (int kt = 0; kt < KT1+KT2; kt++){
    const u16* ab; int sA, koff;
    if (KT2 == 0 || kt < KT1){ ab = A1; sA = sA1; koff = kt*32; }
    else { ab = A2; sA = sA2; koff = (kt-KT1)*32; }
    v8s a[4];
    #pragma unroll
    for (int mt = 0; mt < 4; mt++)
      a[mt] = *(const v8s*)(ab + (size_t)ar[mt]*sA + koff + quad*8);
    if (KT2 > 0 && kt >= KT1){
      #pragma unroll
      for (int mt = 0; mt < 4; mt++)
        #pragma unroll
        for (int j = 0; j < 8; j++){
          float f = u2f((u16)a[mt][j]);
          f = f > 0.f ? f : 0.01f*f;
          a[mt][j] = (short)f2u(f);
        }
    }
    const int kb = kt*32 + quad*8;
    #pragma unroll
    for (int nt = 0; nt < NT; nt++){
      v8s b = *(const v8s*)(BT + (size_t)(nbase + nt*16 + l15)*sBT + kb);
      #pragma unroll
      for (int mt = 0; mt < 4; mt++)
        acc[mt][nt] = __builtin_amdgcn_mfma_f32_16x16x32_bf16(a[mt], b, acc[mt][nt], 0, 0, 0);
    }
  }
  #pragma unroll
  for (int mt = 0; mt < 4; mt++){
    const int r0 = mb + mt*16 + quad*4;
    #pragma unroll
    for (int nt = 0; nt < NT; nt++){
      const int col = nbase + nt*16 + l15;
      #pragma unroll
      for (int i = 0; i < 4; i++){
        int r = r0 + i;
        if (r < m){
          float xv = acc[mt][nt][i];
          if (EPI){ xv += bias[min(col,135)]; xv = lrelu01(xv); }
          C[(size_t)r*sC + col] = f2u(xv);
        }
      }
    }
  }
}

// ---------------- attention dot products ----------------
template<int H,int C>
__global__ void __launch_bounds__(256) k_attn(const u16* __restrict__ h, int sh,
    const float* __restrict__ av, const float* __restrict__ dv,
    float* __restrict__ asrc, float* __restrict__ adst, int m)
{
  constexpr int CT = H*C;
  int wid = threadIdx.x >> 6, lane = threadIdx.x & 63;
  int node = blockIdx.x*4 + wid;
  if (node >= m) return;
  const u16* hr = h + (size_t)node*sh;
  float s0=0,d0=0,s1=0,d1=0;
  for (int c = lane; c < CT; c += 64){
    float hv = u2f(hr[c]);
    float a = av[c], d = dv[c];
    if (H == 2 && c >= C){ s1 = fmaf(hv,a,s1); d1 = fmaf(hv,d,d1); }
    else                 { s0 = fmaf(hv,a,s0); d0 = fmaf(hv,d,d0); }
  }
  #pragma unroll
  for (int o = 32; o > 0; o >>= 1){
    s0 += __shfl_down(s0,o,64); d0 += __shfl_down(d0,o,64);
    if (H == 2){ s1 += __shfl_down(s1,o,64); d1 += __shfl_down(d1,o,64); }
  }
  if (lane == 0){
    asrc[(size_t)node*H] = s0; adst[(size_t)node*H] = d0;
    if (H == 2){ asrc[(size_t)node*H+1] = s1; adst[(size_t)node*H+1] = d1; }
  }
}

// ---------------- GAT aggregation: one wave per (dst,b), XCD-swizzled, pipelined ----------------
template<int H,int CT,int LACT>
__global__ void __launch_bounds__(256) k_agg(const u16* __restrict__ h, int sh,
    const float* __restrict__ asrc, const float* __restrict__ adst,
    const int* __restrict__ offs, const int* __restrict__ srcl,
    const float* __restrict__ bias, u16* __restrict__ outp0, int so,
    int cbMask, int cbShift)
{
  constexpr int CC   = CT/H;
  constexpr int VEC  = (CT >= 256) ? 4 : 2;
  constexpr int MAINC= 64*VEC;
  constexpr int REMV = (CT - MAINC)/VEC;
  constexpr int NPK  = VEC/2;   // packed u32 per lane (main)

  const int wv = threadIdx.x >> 6, lane = threadIdx.x & 63;
  const int id = blockIdx.x;
  const int bb = id & cbMask;           // batch -> XCD locality (blocks id%8 -> same XCD)
  const int dst = (id >> cbShift)*4 + wv;
  const int nbase = bb*N0_;
  const int node = nbase + dst;
  const int start = offs[dst], end = offs[dst+1];
  const int ne = end - start;

  float adh[H];
  #pragma unroll
  for (int hh = 0; hh < H; hh++) adh[hh] = adst[(size_t)node*H + hh];

  float accm[VEC], accr[VEC];
  #pragma unroll
  for (int i = 0; i < VEC; i++){ accm[i] = 0.f; accr[i] = 0.f; }

  const u16* hlane  = h + (size_t)VEC*lane;
  const u16* hlaner = h + MAINC + (size_t)VEC*lane;

  // pipelined accumulation over one chunk of <=64 edges (sn/c0/c1 held per-lane)
  auto run_chunk = [&](int sn, float c0, float c1, int cnt){
    u32 pv[2][NPK], pr[2][NPK];
    auto ld = [&](int j, int s){
      int sj = __shfl(sn, j, 64);
      const size_t ro = (size_t)sj*sh;
      if (VEC == 4){
        uint2 t = *(const uint2*)(hlane + ro);
        pv[s][0] = t.x; pv[s][1] = t.y;
        if (lane < REMV){
          uint2 r = *(const uint2*)(hlaner + ro);
          pr[s][0] = r.x; pr[s][1] = r.y;
        }
      } else {
        pv[s][0] = *(const u32*)(hlane + ro);
        if (lane < REMV) pr[s][0] = *(const u32*)(hlaner + ro);
      }
    };
    if (cnt > 0) ld(0, 0);
    if (cnt > 1) ld(1, 1);
    for (int j = 0; j < cnt; j++){
      const int s = j & 1;
      u32 qv[NPK], qr[NPK];
      #pragma unroll
      for (int q = 0; q < NPK; q++){ qv[q] = pv[s][q]; qr[q] = pr[s][q]; }
      if (j + 2 < cnt) ld(j + 2, s);
      float c0j = __shfl(c0, j, 64);
      float c1j = (H == 2) ? __shfl(c1, j, 64) : c0j;
      float w  = (H == 2 && VEC*lane >= CC) ? c1j : c0j;
      float wr = (H == 2) ? c1j : c0j;
      #pragma unroll
      for (int q = 0; q < NPK; q++) acc2(w, qv[q], accm[2*q], accm[2*q+1]);
      if (lane < REMV){
        #pragma unroll
        for (int q = 0; q < NPK; q++) acc2(wr, qr[q], accr[2*q], accr[2*q+1]);
      }
    }
  };

  if (ne <= 64){
    const bool has = lane < ne;
    const int sn = nbase + (has ? srcl[start + lane] : 0);
    float al[H], p[H];
    #pragma unroll
    for (int hh = 0; hh < H; hh++)
      al[hh] = has ? lrelu02(asrc[(size_t)sn*H + hh] + adh[hh]) : -1e30f;
    float c0 = 0.f, c1 = 0.f;
    #pragma unroll
    for (int hh = 0; hh < H; hh++){
      float m = wred_max(al[hh]);
      p[hh] = has ? __expf(al[hh] - m) : 0.f;
      float sinv = 1.f/(wred_sum(p[hh]) + 1e-16f);
      if (hh == 0) c0 = p[0]*sinv; else c1 = p[1]*sinv;
    }
    run_chunk(sn, c0, c1, ne);
  } else {
    float lm[H], m[H], sinv[H];
    #pragma unroll
    for (int hh = 0; hh < H; hh++) lm[hh] = -1e30f;
    for (int e = start + lane; e < end; e += 64){
      int sn = nbase + srcl[e];
      #pragma unroll
      for (int hh = 0; hh < H; hh++)
        lm[hh] = fmaxf(lm[hh], lrelu02(asrc[(size_t)sn*H + hh] + adh[hh]));
    }
    #pragma unroll
    for (int hh = 0; hh < H; hh++) m[hh] = wred_max(lm[hh]);
    float ls[H];
    #pragma unroll
    for (int hh = 0; hh < H; hh++) ls[hh] = 0.f;
    for (int e = start + lane; e < end; e += 64){
      int sn = nbase + srcl[e];
      #pragma unroll
      for (int hh = 0; hh < H; hh++)
        ls[hh] += __expf(lrelu02(asrc[(size_t)sn*H + hh] + adh[hh]) - m[hh]);
    }
    #pragma unroll
    for (int hh = 0; hh < H; hh++) sinv[hh] = 1.f/(wred_sum(ls[hh]) + 1e-16f);
    for (int cs = start; cs < end; cs += 64){
      int cnt = min(64, end - cs);
      bool has = lane < cnt;
      int sn = nbase + (has ? srcl[cs + lane] : 0);
      float c0 = 0.f, c1 = 0.f;
      if (has){
        #pragma unroll
        for (int hh = 0; hh < H; hh++){
          float p = __expf(lrelu02(asrc[(size_t)sn*H + hh] + adh[hh]) - m[hh]) * sinv[hh];
          if (hh == 0) c0 = p; else c1 = p;
        }
      }
      run_chunk(sn, c0, c1, cnt);
    }
  }

  u16* outp = outp0 + (size_t)node*so;
  auto fin = [&](float v, int c)->u16{
    float r = v + bias[c];
    if (LACT) r = lrelu01(r);
    return f2u(r);
  };
  if (VEC == 4){
    int c = 4*lane;
    ushort4 st;
    st.x = fin(accm[0], c+0); st.y = fin(accm[1], c+1);
    st.z = fin(accm[2], c+2); st.w = fin(accm[3], c+3);
    *(ushort4*)(outp + c) = st;
    if (lane < REMV){
      int cr = MAINC + 4*lane;
      ushort4 sr;
      sr.x = fin(accr[0], cr+0); sr.y = fin(accr[1], cr+1);
      sr.z = fin(accr[2], cr+2); sr.w = fin(accr[3], cr+3);
      *(ushort4*)(outp + cr) = sr;
    }
  } else {
    int c = 2*lane;
    ushort2 st; st.x = fin(accm[0], c+0); st.y = fin(accm[1], c+1);
    *(ushort2*)(outp + c) = st;
    if (lane < REMV){
      int cr = MAINC + 2*lane;
      ushort2 sr; sr.x = fin(accr[0], cr+0); sr.y = fin(accr[1], cr+1);
      *(ushort2*)(outp + cr) = sr;
    }
  }
}

// ---------------- final dot ----------------
__global__ void __launch_bounds__(256) k_head2(const u16* __restrict__ res, int sr,
    const float* __restrict__ Wo2, const float* __restrict__ bo2,
    float* __restrict__ out, int m)
{
  int wid = threadIdx.x >> 6, lane = threadIdx.x & 63;
  int node = blockIdx.x*4 + wid;
  if (node >= m) return;
  const u16* rr = res + (size_t)node*sr;
  float a = 0.f;
  for (int c = lane; c < 136; c += 64) a = fmaf(u2f(rr[c]), Wo2[c], a);
  #pragma unroll
  for (int o = 32; o > 0; o >>= 1) a += __shfl_down(a,o,64);
  if (lane == 0) out[node] = a + bo2[0];
}

// ---------------- launch ----------------
extern "C" void kernel_launch(void* const* d_in, const int* in_sizes, int n_in,
                              void* d_out, int out_size, void* d_ws, size_t ws_size,
                              hipStream_t stream)
{
  (void)in_sizes; (void)n_in; (void)out_size;
  const float* x    = (const float*)d_in[0];
  const float* wl1  = (const float*)d_in[1];
  const float* gl1  = (const float*)d_in[3];
  const float* bel1 = (const float*)d_in[4];
  const float* wl2  = (const float*)d_in[5];
  const float* gl2  = (const float*)d_in[7];
  const float* bel2 = (const float*)d_in[8];
  const float* wp1  = (const float*)d_in[9];
  const float* gp1  = (const float*)d_in[11];
  const float* bep1 = (const float*)d_in[12];
  const float* wp2  = (const float*)d_in[13];
  const float* gp2  = (const float*)d_in[15];
  const float* bep2 = (const float*)d_in[16];
  const float* wg   = (const float*)d_in[17];
  const float* gg   = (const float*)d_in[19];
  const float* beg  = (const float*)d_in[20];
  const float* W1   = (const float*)d_in[21];
  const float* as1  = (const float*)d_in[22];
  const float* ad1  = (const float*)d_in[23];
  const float* bb1  = (const float*)d_in[24];
  const float* W2   = (const float*)d_in[25];
  const float* as2  = (const float*)d_in[26];
  const float* ad2  = (const float*)d_in[27];
  const float* bb2  = (const float*)d_in[28];
  const float* Wo   = (const float*)d_in[29];
  const float* bo   = (const float*)d_in[30];
  const float* Wo2  = (const float*)d_in[31];
  const float* bo2  = (const float*)d_in[32];
  const int*   ei   = (const int*)d_in[33];

  const size_t STATIC_BYTES = 1300000;
  int nc = 1;
  while (nc < 8 && STATIC_BYTES + (size_t)2104*(NODES/nc) > ws_size) nc <<= 1;
  const int CB = B_/nc, CN = CB*N0_;
  int cbShift = 0; while ((1 << cbShift) < CB) cbShift++;
  const int cbMask = CB - 1;

  char* wsb = (char*)d_ws; size_t off = 0;
  auto alloc = [&](size_t nbytes)->void*{
    void* p = wsb + off; off = (off + nbytes + 255) & ~(size_t)255; return p;
  };
  int*   zbase  = (int*)  alloc(20080*sizeof(int));
  float* gsum   = (float*)zbase;
  float* gsq    = gsum + 40;
  int*   counts = zbase + 80;
  int*   cursor = counts + 10000;
  float* sA     = (float*)alloc(40*sizeof(float));
  float* sB     = (float*)alloc(40*sizeof(float));
  int*   offs   = (int*)  alloc(10001*sizeof(int));
  int*   srcl   = (int*)  alloc((size_t)NE_*sizeof(int));
  u16*   W1T    = (u16*)  alloc((size_t)272*160*2);
  u16*   W2T    = (u16*)  alloc((size_t)144*288*2);
  u16*   WoT    = (u16*)  alloc((size_t)144*320*2);
  u16*   feat   = (u16*)  alloc((size_t)CN*160*2);
  u16*   h1     = (u16*)  alloc((size_t)CN*288*2);
  u16*   g1     = (u16*)  alloc((size_t)CN*288*2);
  u16*   h2     = (u16*)  alloc((size_t)CN*144*2);
  u16*   g2l    = (u16*)  alloc((size_t)CN*160*2);
  float* asrc1  = (float*)alloc((size_t)CN*2*sizeof(float));
  float* adst1  = (float*)alloc((size_t)CN*2*sizeof(float));
  float* asrc2  = (float*)alloc((size_t)CN*sizeof(float));
  float* adst2  = (float*)alloc((size_t)CN*sizeof(float));
  u16*   res    = h1;

  k_zero<<<79,256,0,stream>>>(zbase, 20080);

  k_bn_stats<<<313,256,0,stream>>>(x, wl1,wl2,wp1,wp2,wg, gsum, gsq);
  k_bn_fin  <<<1,64,0,stream>>>(gsum, gsq, sA, sB, gl1,gl2,gp1,gp2,gg, bel1,bel2,bep1,bep2,beg);

  k_count  <<<665,256,0,stream>>>(ei, counts);
  k_scan   <<<1,1024,0,stream>>>(counts, offs);
  k_scatter<<<665,256,0,stream>>>(ei, offs, cursor, srcl);

  k_wt<<<171,256,0,stream>>>(W1T, W1, 272, 160, 272, 136, 0);
  k_wt<<<162,256,0,stream>>>(W2T, W2, 144, 288, 136, 272, 0);
  k_wt<<<180,256,0,stream>>>(WoT, Wo, 144, 320, 136, 0,   1);

  const int gx = (CN + 255)/256;
  const int aggB = 2500*CB;
  for (int c = 0; c < nc; c++){
    const int base = c*CN;

    k_feat<<<gx,256,0,stream>>>(x, wl1,wl2,wp1,wp2,wg, sA, sB, feat, base, CN);

    k_mfma<5,0,9,0><<<gx,256,0,stream>>>(feat,160, (const u16*)0,0, W1T,160, h1,288,   0, (const float*)0, CN);
    k_mfma<5,0,8,0><<<gx,256,0,stream>>>(feat,160, (const u16*)0,0, W1T,160, h1,288, 144, (const float*)0, CN);
    k_attn<2,136>  <<<CN/4,256,0,stream>>>(h1,288, as1, ad1, asrc1, adst1, CN);
    k_agg<2,272,0> <<<aggB,256,0,stream>>>(h1,288, asrc1, adst1, offs, srcl, bb1, g1,288, cbMask, cbShift);

    k_mfma<9,0,9,0><<<gx,256,0,stream>>>(g1,288, (const u16*)0,0, W2T,288, h2,144, 0, (const float*)0, CN);
    k_attn<1,136>  <<<CN/4,256,0,stream>>>(h2,144, as2, ad2, asrc2, adst2, CN);
    k_agg<1,136,1> <<<aggB,256,0,stream>>>(h2,144, asrc2, adst2, offs, srcl, bb2, g2l,160, cbMask, cbShift);

    k_mfma<5,5,9,1><<<gx,256,0,stream>>>(g2l,160, feat,160, WoT,320, res,144, 0, bo, CN);
    k_head2<<<CN/4,256,0,stream>>>(res,144, Wo2, bo2, (float*)d_out + base, CN);
  }
}

// Round 7
// 701.810 us; speedup vs baseline: 1.1175x; 1.1175x over previous
//
#include <hip/hip_runtime.h>
#include <hip/hip_bf16.h>
#include <math.h>

typedef unsigned short u16;
typedef unsigned int   u32;
typedef short v8s __attribute__((ext_vector_type(8)));
typedef float v4f __attribute__((ext_vector_type(4)));
#define DEV static __device__ __forceinline__

DEV float u2f(u16 u){ union{u32 i; float f;} v; v.i = ((u32)u)<<16; return v.f; }
DEV u16   f2u(float f){ union{float ff; u32 i;} v; v.ff = f; u32 r = v.i + 0x7fffu + ((v.i>>16)&1u); return (u16)(r>>16); }
DEV float lrelu02(float x){ return x > 0.f ? x : 0.2f*x; }
DEV float lrelu01(float x){ return x > 0.f ? x : 0.01f*x; }
DEV float wred_max(float v){
  #pragma unroll
  for (int o = 32; o > 0; o >>= 1) v = fmaxf(v, __shfl_xor(v, o, 64));
  return v;
}
DEV float wred_sum(float v){
  #pragma unroll
  for (int o = 32; o > 0; o >>= 1) v += __shfl_xor(v, o, 64);
  return v;
}

constexpr int B_   = 8;
constexpr int P_   = 32;
constexpr int N0_  = 10000;
constexpr int NODES = B_ * N0_;      // 80000
constexpr int E_   = 160000;
constexpr int NE_  = E_ + N0_;       // 170000

// ---------------- utility ----------------
__global__ void k_zero(int* __restrict__ p, int n){
  int i = blockIdx.x*blockDim.x + threadIdx.x;
  if (i < n) p[i] = 0;
}

// weight transpose+cast: dst[n][k] (bf16, padded) from src[k][n] (f32)
__global__ void k_wt(u16* __restrict__ dst, const float* __restrict__ src,
                     int NR, int NKp, int Nsrc, int Klim, int mode){
  int i = blockIdx.x*blockDim.x + threadIdx.x;
  if (i >= NR*NKp) return;
  int n = i / NKp, k = i - n*NKp;
  float v = 0.f;
  if (n < Nsrc){
    if (mode == 0){ if (k < Klim) v = src[(size_t)k*Nsrc + n]; }
    else {
      if (k < 136) v = src[(size_t)k*Nsrc + n];
      else if (k >= 160 && k < 296) v = src[(size_t)(k-24)*Nsrc + n];
    }
  }
  dst[i] = f2u(v);
}

// ---------------- backbone ----------------
DEV void load_convw(float* lw, const float* wl1, const float* wl2, const float* wp1,
                    const float* wp2, const float* wg, int tid, int nth){
  for (int i = tid; i < 384; i += nth){
    float v;
    if      (i < 24)  v = wl1[i];
    else if (i < 64)  v = wl2[i-24];
    else if (i < 88)  v = wp1[i-64];
    else if (i < 128) v = wp2[i-88];
    else              v = wg [i-128];
    lw[i] = v;
  }
}

template<int KS,int DIL,int T>
DEV void conv_stats(const float* xc, const float* wk, float& s, float& q){
  #pragma unroll
  for (int t = 0; t < T; t++){
    float v = 0.f;
    #pragma unroll
    for (int j = 0; j < KS; j++) v = fmaf(wk[j], xc[t + j*DIL], v);
    s += v; q = fmaf(v, v, q);
  }
}

__global__ void __launch_bounds__(256) k_bn_stats(
    const float* __restrict__ x,
    const float* __restrict__ wl1, const float* __restrict__ wl2,
    const float* __restrict__ wp1, const float* __restrict__ wp2,
    const float* __restrict__ wg,
    float* __restrict__ gsum, float* __restrict__ gsq)
{
  __shared__ float lw[384];
  __shared__ float lacc[80];
  const int tid = threadIdx.x;
  load_convw(lw, wl1, wl2, wp1, wp2, wg, tid, 256);
  if (tid < 80) lacc[tid] = 0.f;
  __syncthreads();

  int gid = blockIdx.x*256 + tid;
  float xc[P_];
  if (gid < NODES){
    int b = gid / N0_, n = gid - b*N0_;
    const float* xp = x + (size_t)b*P_*N0_ + n;
    #pragma unroll
    for (int p = 0; p < P_; p++) xc[p] = xp[(size_t)p*N0_];
  } else {
    #pragma unroll
    for (int p = 0; p < P_; p++) xc[p] = 0.f;
  }
  const int lane = tid & 63;

  auto red = [&](int ch, float s, float q){
    #pragma unroll
    for (int o = 32; o > 0; o >>= 1){ s += __shfl_down(s,o,64); q += __shfl_down(q,o,64); }
    if (lane == 0){ atomicAdd(&lacc[ch], s); atomicAdd(&lacc[40+ch], q); }
  };

  #pragma unroll
  for (int k = 0; k < 8; k++){ float s=0,q=0; conv_stats<3,1,30>(xc, lw      + k*3 , s,q); red(k,     s,q); }
  #pragma unroll
  for (int k = 0; k < 8; k++){ float s=0,q=0; conv_stats<5,1,28>(xc, lw + 24 + k*5 , s,q); red(8+k,   s,q); }
  #pragma unroll
  for (int k = 0; k < 8; k++){ float s=0,q=0; conv_stats<3,2,28>(xc, lw + 64 + k*3 , s,q); red(16+k,  s,q); }
  #pragma unroll
  for (int k = 0; k < 8; k++){ float s=0,q=0; conv_stats<5,2,24>(xc, lw + 88 + k*5 , s,q); red(24+k,  s,q); }
  #pragma unroll
  for (int k = 0; k < 8; k++){ float s=0,q=0; conv_stats<32,1,1>(xc, lw + 128+ k*32, s,q); red(32+k,  s,q); }

  __syncthreads();
  if (tid < 40)      atomicAdd(&gsum[tid],    lacc[tid]);
  else if (tid < 80) atomicAdd(&gsq [tid-40], lacc[tid]);
}

__global__ void k_bn_fin(const float* __restrict__ gsum, const float* __restrict__ gsq,
                         float* __restrict__ sA, float* __restrict__ sB,
                         const float* g0, const float* g1, const float* g2, const float* g3, const float* g4,
                         const float* e0, const float* e1, const float* e2, const float* e3, const float* e4)
{
  int t = threadIdx.x;
  if (t >= 40) return;
  int bi = t >> 3, k = t & 7;
  const int Ts[5] = {30,28,28,24,1};
  float cnt  = (float)NODES * (float)Ts[bi];
  float mean = gsum[t] / cnt;
  float var  = gsq[t] / cnt - mean*mean;
  const float* gp = bi==0?g0: bi==1?g1: bi==2?g2: bi==3?g3: g4;
  const float* ep = bi==0?e0: bi==1?e1: bi==2?e2: bi==3?e3: e4;
  float a = gp[k] * rsqrtf(fmaxf(var, 0.f) + 1e-5f);
  sA[t] = a;
  sB[t] = ep[k] - a*mean;
}

template<int KS,int DIL,int T>
DEV void conv_pool4(const float* xc, const float* wk, float A, float Bc, float* o4){
  float y[T];
  #pragma unroll
  for (int t = 0; t < T; t++){
    float v = 0.f;
    #pragma unroll
    for (int j = 0; j < KS; j++) v = fmaf(wk[j], xc[t + j*DIL], v);
    y[t] = fmaf(A, v, Bc);
  }
  #pragma unroll
  for (int i = 0; i < 4; i++){
    const int lo = (i*T)/4, hi = ((i+1)*T + 3)/4;
    float m = y[lo];
    #pragma unroll
    for (int t = 0; t < T; t++){ if (t > lo && t < hi) m = fmaxf(m, y[t]); }
    o4[i] = m;
  }
}

// writes feat row-major [m][160] bf16 (tanh applied)
__global__ void __launch_bounds__(256) k_feat(
    const float* __restrict__ x,
    const float* __restrict__ wl1, const float* __restrict__ wl2,
    const float* __restrict__ wp1, const float* __restrict__ wp2,
    const float* __restrict__ wg,
    const float* __restrict__ sA, const float* __restrict__ sB,
    u16* __restrict__ feat, int base, int m)
{
  __shared__ float lw[384];
  __shared__ float lA[40], lB[40];
  const int tid = threadIdx.x;
  load_convw(lw, wl1, wl2, wp1, wp2, wg, tid, 256);
  if (tid < 40){ lA[tid] = sA[tid]; lB[tid] = sB[tid]; }
  __syncthreads();

  int gid = blockIdx.x*256 + tid;
  if (gid >= m) return;
  int g = base + gid;
  int b = g / N0_, n = g - b*N0_;
  float xc[P_];
  const float* xp = x + (size_t)b*P_*N0_ + n;
  #pragma unroll
  for (int p = 0; p < P_; p++) xc[p] = xp[(size_t)p*N0_];

  u32 pk[4];
  u16* orow = feat + (size_t)gid*160;
  auto emit = [&](int ch, float v){
    u16 h = f2u(tanhf(v));
    int s = ch & 7;
    if ((s & 1) == 0) pk[s>>1] = h;
    else              pk[s>>1] |= ((u32)h) << 16;
    if (s == 7) *(uint4*)(orow + (ch - 7)) = make_uint4(pk[0],pk[1],pk[2],pk[3]);
  };

  float o4[4];
  #pragma unroll
  for (int k = 0; k < 8; k++){
    conv_pool4<3,1,30>(xc, lw + k*3, lA[k], lB[k], o4);
    #pragma unroll
    for (int i = 0; i < 4; i++) emit(k*4+i, o4[i]);
  }
  #pragma unroll
  for (int k = 0; k < 8; k++){
    conv_pool4<5,1,28>(xc, lw + 24 + k*5, lA[8+k], lB[8+k], o4);
    #pragma unroll
    for (int i = 0; i < 4; i++) emit(32 + k*4+i, o4[i]);
  }
  #pragma unroll
  for (int k = 0; k < 8; k++){
    conv_pool4<3,2,28>(xc, lw + 64 + k*3, lA[16+k], lB[16+k], o4);
    #pragma unroll
    for (int i = 0; i < 4; i++) emit(64 + k*4+i, o4[i]);
  }
  #pragma unroll
  for (int k = 0; k < 8; k++){
    conv_pool4<5,2,24>(xc, lw + 88 + k*5, lA[24+k], lB[24+k], o4);
    #pragma unroll
    for (int i = 0; i < 4; i++) emit(96 + k*4+i, o4[i]);
  }
  #pragma unroll
  for (int k = 0; k < 8; k++){
    float v = 0.f;
    #pragma unroll
    for (int j = 0; j < 32; j++) v = fmaf(lw[128 + k*32 + j], xc[j], v);
    emit(128 + k, fmaf(lA[32+k], v, lB[32+k]));
  }
}

// ---------------- CSR ----------------
__global__ void k_count(const int* __restrict__ ei, int* __restrict__ counts){
  int e = blockIdx.x*blockDim.x + threadIdx.x;
  if (e >= NE_) return;
  int dst = (e < E_) ? ei[E_ + e] : (e - E_);
  atomicAdd(&counts[dst], 1);
}

__global__ void __launch_bounds__(1024) k_scan(const int* __restrict__ counts, int* __restrict__ offs){
  __shared__ int part[1024];
  int t = threadIdx.x;
  int loc[10]; int s = 0;
  #pragma unroll
  for (int i = 0; i < 10; i++){
    int idx = t*10 + i;
    int c = (idx < N0_) ? counts[idx] : 0;
    loc[i] = s; s += c;
  }
  part[t] = s;
  __syncthreads();
  for (int o = 1; o < 1024; o <<= 1){
    int v = (t >= o) ? part[t-o] : 0;
    __syncthreads();
    part[t] += v;
    __syncthreads();
  }
  int pre = (t == 0) ? 0 : part[t-1];
  #pragma unroll
  for (int i = 0; i < 10; i++){
    int idx = t*10 + i;
    if (idx < N0_) offs[idx] = pre + loc[i];
  }
  if (t == 0) offs[N0_] = part[1023];
}

__global__ void k_scatter(const int* __restrict__ ei, const int* __restrict__ offs,
                          int* __restrict__ cursor, int* __restrict__ srcl){
  int e = blockIdx.x*blockDim.x + threadIdx.x;
  if (e >= NE_) return;
  int src, dst;
  if (e < E_){ src = ei[e]; dst = ei[E_ + e]; } else { src = dst = e - E_; }
  int pos = atomicAdd(&cursor[dst], 1);
  srcl[offs[dst] + pos] = src;
}

// ---------------- MFMA GEMM: A[m][K] bf16 row-major, BT[n][K] bf16, C[m][N] bf16 ----------------
template<int KT1,int KT2,int NT,int EPI>
__global__ void __launch_bounds__(256) k_mfma(
    const u16* __restrict__ A1, int sA1,
    const u16* __restrict__ A2, int sA2,
    const u16* __restrict__ BT, int sBT,
    u16* __restrict__ C, int sC, int nbase,
    const float* __restrict__ bias, int m)
{
  const int wv = threadIdx.x >> 6, lane = threadIdx.x & 63;
  const int quad = lane >> 4, l15 = lane & 15;
  const int mb = blockIdx.x*256 + wv*64;
  int ar[4];
  #pragma unroll
  for (int mt = 0; mt < 4; mt++) ar[mt] = min(mb + mt*16 + l15, m-1);

  v4f acc[4][NT];
  #pragma unroll
  for (int mt = 0; mt < 4; mt++)
    #pragma unroll
    for (int nt = 0; nt < NT; nt++)
      acc[mt][nt] = (v4f){0.f,0.f,0.f,0.f};

  for (int kt = 0; kt < KT1+KT2; kt++){
    const u16* ab; int sA, koff;
    if (KT2 == 0 || kt < KT1){ ab = A1; sA = sA1; koff = kt*32; }
    else { ab = A2; sA = sA2; koff = (kt-KT1)*32; }
    v8s a[4];
    #pragma unroll
    for (int mt = 0; mt < 4; mt++)
      a[mt] = *(const v8s*)(ab + (size_t)ar[mt]*sA + koff + quad*8);
    if (KT2 > 0 && kt >= KT1){
      #pragma unroll
      for (int mt = 0; mt < 4; mt++)
        #pragma unroll
        for (int j = 0; j < 8; j++){
          float f = u2f((u16)a[mt][j]);
          f = f > 0.f ? f : 0.01f*f;
          a[mt][j] = (short)f2u(f);
        }
    }
    const int kb = kt*32 + quad*8;
    #pragma unroll
    for (int nt = 0; nt < NT; nt++){
      v8s b = *(const v8s*)(BT + (size_t)(nbase + nt*16 + l15)*sBT + kb);
      #pragma unroll
      for (int mt = 0; mt < 4; mt++)
        acc[mt][nt] = __builtin_amdgcn_mfma_f32_16x16x32_bf16(a[mt], b, acc[mt][nt], 0, 0, 0);
    }
  }
  #pragma unroll
  for (int mt = 0; mt < 4; mt++){
    const int r0 = mb + mt*16 + quad*4;
    #pragma unroll
    for (int nt = 0; nt < NT; nt++){
      const int col = nbase + nt*16 + l15;
      #pragma unroll
      for (int i = 0; i < 4; i++){
        int r = r0 + i;
        if (r < m){
          float xv = acc[mt][nt][i];
          if (EPI){ xv += bias[min(col,135)]; xv = lrelu01(xv); }
          C[(size_t)r*sC + col] = f2u(xv);
        }
      }
    }
  }
}

// ---------------- attention dot products ----------------
template<int H,int C>
__global__ void __launch_bounds__(256) k_attn(const u16* __restrict__ h, int sh,
    const float* __restrict__ av, const float* __restrict__ dv,
    float* __restrict__ asrc, float* __restrict__ adst, int m)
{
  constexpr int CT = H*C;
  int wid = threadIdx.x >> 6, lane = threadIdx.x & 63;
  int node = blockIdx.x*4 + wid;
  if (node >= m) return;
  const u16* hr = h + (size_t)node*sh;
  float s0=0,d0=0,s1=0,d1=0;
  for (int c = lane; c < CT; c += 64){
    float hv = u2f(hr[c]);
    float a = av[c], d = dv[c];
    if (H == 2 && c >= C){ s1 = fmaf(hv,a,s1); d1 = fmaf(hv,d,d1); }
    else                 { s0 = fmaf(hv,a,s0); d0 = fmaf(hv,d,d0); }
  }
  #pragma unroll
  for (int o = 32; o > 0; o >>= 1){
    s0 += __shfl_down(s0,o,64); d0 += __shfl_down(d0,o,64);
    if (H == 2){ s1 += __shfl_down(s1,o,64); d1 += __shfl_down(d1,o,64); }
  }
  if (lane == 0){
    asrc[(size_t)node*H] = s0; adst[(size_t)node*H] = d0;
    if (H == 2){ asrc[(size_t)node*H+1] = s1; adst[(size_t)node*H+1] = d1; }
  }
}

// ---------------- GAT aggregation: one wave per (dst,b), XCD-swizzled ----------------
template<int H,int CT,int LACT>
__global__ void __launch_bounds__(256) k_agg(const u16* __restrict__ h, int sh,
    const float* __restrict__ asrc, const float* __restrict__ adst,
    const int* __restrict__ offs, const int* __restrict__ srcl,
    const float* __restrict__ bias, u16* __restrict__ outp0, int so,
    int cbMask, int cbShift)
{
  constexpr int CC   = CT/H;
  constexpr int VEC  = (CT >= 256) ? 4 : 2;
  constexpr int MAINC= 64*VEC;
  constexpr int REMV = (CT - MAINC)/VEC;

  const int wv = threadIdx.x >> 6, lane = threadIdx.x & 63;
  const int id = blockIdx.x;
  const int bb = id & cbMask;           // batch -> XCD locality (blocks id%8 -> same XCD)
  const int dst = (id >> cbShift)*4 + wv;
  const int nbase = bb*N0_;
  const int node = nbase + dst;
  const int start = offs[dst], end = offs[dst+1];
  const int ne = end - start;

  float adh[H];
  #pragma unroll
  for (int hh = 0; hh < H; hh++) adh[hh] = adst[(size_t)node*H + hh];

  float accm[VEC], accr[VEC];
  #pragma unroll
  for (int i = 0; i < VEC; i++){ accm[i] = 0.f; accr[i] = 0.f; }

  auto acc_edge = [&](int sj, float c0, float c1){
    const u16* hp = h + (size_t)sj*sh;
    if (VEC == 4){
      const ushort4 hv = *(const ushort4*)(hp + 4*lane);
      float w = (H == 2 && 4*lane >= CC) ? c1 : c0;
      accm[0] = fmaf(w, u2f(hv.x), accm[0]);
      accm[1] = fmaf(w, u2f(hv.y), accm[1]);
      accm[2] = fmaf(w, u2f(hv.z), accm[2]);
      accm[3] = fmaf(w, u2f(hv.w), accm[3]);
      if (lane < REMV){
        const ushort4 hr = *(const ushort4*)(hp + MAINC + 4*lane);
        float wr = (H == 2) ? c1 : c0;
        accr[0] = fmaf(wr, u2f(hr.x), accr[0]);
        accr[1] = fmaf(wr, u2f(hr.y), accr[1]);
        accr[2] = fmaf(wr, u2f(hr.z), accr[2]);
        accr[3] = fmaf(wr, u2f(hr.w), accr[3]);
      }
    } else {
      const ushort2 hv = *(const ushort2*)(hp + 2*lane);
      float w = (H == 2 && 2*lane >= CC) ? c1 : c0;
      accm[0] = fmaf(w, u2f(hv.x), accm[0]);
      accm[1] = fmaf(w, u2f(hv.y), accm[1]);
      if (lane < REMV){
        const ushort2 hr = *(const ushort2*)(hp + MAINC + 2*lane);
        float wr = (H == 2) ? c1 : c0;
        accr[0] = fmaf(wr, u2f(hr.x), accr[0]);
        accr[1] = fmaf(wr, u2f(hr.y), accr[1]);
      }
    }
  };

  if (ne <= 64){
    const bool has = lane < ne;
    const int sn = nbase + (has ? srcl[start + lane] : 0);
    float al[H], p[H];
    #pragma unroll
    for (int hh = 0; hh < H; hh++)
      al[hh] = has ? lrelu02(asrc[(size_t)sn*H + hh] + adh[hh]) : -1e30f;
    float c0 = 0.f, c1 = 0.f;
    #pragma unroll
    for (int hh = 0; hh < H; hh++){
      float m = wred_max(al[hh]);
      p[hh] = has ? __expf(al[hh] - m) : 0.f;
      float sinv = 1.f/(wred_sum(p[hh]) + 1e-16f);
      if (hh == 0) c0 = p[0]*sinv; else c1 = p[1]*sinv;
    }
    if (H == 1) c1 = c0;
    for (int j = 0; j < ne; j++)
      acc_edge(__shfl(sn, j, 64), __shfl(c0, j, 64), (H==2) ? __shfl(c1, j, 64) : __shfl(c0, j, 64));
  } else {
    float lm[H], m[H], sinv[H];
    #pragma unroll
    for (int hh = 0; hh < H; hh++) lm[hh] = -1e30f;
    for (int e = start + lane; e < end; e += 64){
      int sn = nbase + srcl[e];
      #pragma unroll
      for (int hh = 0; hh < H; hh++)
        lm[hh] = fmaxf(lm[hh], lrelu02(asrc[(size_t)sn*H + hh] + adh[hh]));
    }
    #pragma unroll
    for (int hh = 0; hh < H; hh++) m[hh] = wred_max(lm[hh]);
    float ls[H];
    #pragma unroll
    for (int hh = 0; hh < H; hh++) ls[hh] = 0.f;
    for (int e = start + lane; e < end; e += 64){
      int sn = nbase + srcl[e];
      #pragma unroll
      for (int hh = 0; hh < H; hh++)
        ls[hh] += __expf(lrelu02(asrc[(size_t)sn*H + hh] + adh[hh]) - m[hh]);
    }
    #pragma unroll
    for (int hh = 0; hh < H; hh++) sinv[hh] = 1.f/(wred_sum(ls[hh]) + 1e-16f);
    for (int cs = start; cs < end; cs += 64){
      int cnt = min(64, end - cs);
      bool has = lane < cnt;
      int sn = nbase + (has ? srcl[cs + lane] : 0);
      float c0 = 0.f, c1 = 0.f;
      if (has){
        #pragma unroll
        for (int hh = 0; hh < H; hh++){
          float p = __expf(lrelu02(asrc[(size_t)sn*H + hh] + adh[hh]) - m[hh]) * sinv[hh];
          if (hh == 0) c0 = p; else c1 = p;
        }
        if (H == 1) c1 = c0;
      }
      for (int j = 0; j < cnt; j++)
        acc_edge(__shfl(sn, j, 64), __shfl(c0, j, 64), (H==2) ? __shfl(c1, j, 64) : __shfl(c0, j, 64));
    }
  }

  u16* outp = outp0 + (size_t)node*so;
  auto fin = [&](float v, int c)->u16{
    float r = v + bias[c];
    if (LACT) r = lrelu01(r);
    return f2u(r);
  };
  if (VEC == 4){
    int c = 4*lane;
    ushort4 st;
    st.x = fin(accm[0], c+0); st.y = fin(accm[1], c+1);
    st.z = fin(accm[2], c+2); st.w = fin(accm[3], c+3);
    *(ushort4*)(outp + c) = st;
    if (lane < REMV){
      int cr = MAINC + 4*lane;
      ushort4 sr;
      sr.x = fin(accr[0], cr+0); sr.y = fin(accr[1], cr+1);
      sr.z = fin(accr[2], cr+2); sr.w = fin(accr[3], cr+3);
      *(ushort4*)(outp + cr) = sr;
    }
  } else {
    int c = 2*lane;
    ushort2 st; st.x = fin(accm[0], c+0); st.y = fin(accm[1], c+1);
    *(ushort2*)(outp + c) = st;
    if (lane < REMV){
      int cr = MAINC + 2*lane;
      ushort2 sr; sr.x = fin(accr[0], cr+0); sr.y = fin(accr[1], cr+1);
      *(ushort2*)(outp + cr) = sr;
    }
  }
}

// ---------------- final dot ----------------
__global__ void __launch_bounds__(256) k_head2(const u16* __restrict__ res, int sr,
    const float* __restrict__ Wo2, const float* __restrict__ bo2,
    float* __restrict__ out, int m)
{
  int wid = threadIdx.x >> 6, lane = threadIdx.x & 63;
  int node = blockIdx.x*4 + wid;
  if (node >= m) return;
  const u16* rr = res + (size_t)node*sr;
  float a = 0.f;
  for (int c = lane; c < 136; c += 64) a = fmaf(u2f(rr[c]), Wo2[c], a);
  #pragma unroll
  for (int o = 32; o > 0; o >>= 1) a += __shfl_down(a,o,64);
  if (lane == 0) out[node] = a + bo2[0];
}

// ---------------- launch ----------------
extern "C" void kernel_launch(void* const* d_in, const int* in_sizes, int n_in,
                              void* d_out, int out_size, void* d_ws, size_t ws_size,
                              hipStream_t stream)
{
  (void)in_sizes; (void)n_in; (void)out_size;
  const float* x    = (const float*)d_in[0];
  const float* wl1  = (const float*)d_in[1];
  const float* gl1  = (const float*)d_in[3];
  const float* bel1 = (const float*)d_in[4];
  const float* wl2  = (const float*)d_in[5];
  const float* gl2  = (const float*)d_in[7];
  const float* bel2 = (const float*)d_in[8];
  const float* wp1  = (const float*)d_in[9];
  const float* gp1  = (const float*)d_in[11];
  const float* bep1 = (const float*)d_in[12];
  const float* wp2  = (const float*)d_in[13];
  const float* gp2  = (const float*)d_in[15];
  const float* bep2 = (const float*)d_in[16];
  const float* wg   = (const float*)d_in[17];
  const float* gg   = (const float*)d_in[19];
  const float* beg  = (const float*)d_in[20];
  const float* W1   = (const float*)d_in[21];
  const float* as1  = (const float*)d_in[22];
  const float* ad1  = (const float*)d_in[23];
  const float* bb1  = (const float*)d_in[24];
  const float* W2   = (const float*)d_in[25];
  const float* as2  = (const float*)d_in[26];
  const float* ad2  = (const float*)d_in[27];
  const float* bb2  = (const float*)d_in[28];
  const float* Wo   = (const float*)d_in[29];
  const float* bo   = (const float*)d_in[30];
  const float* Wo2  = (const float*)d_in[31];
  const float* bo2  = (const float*)d_in[32];
  const int*   ei   = (const int*)d_in[33];

  const size_t STATIC_BYTES = 1300000;
  int nc = 1;
  while (nc < 8 && STATIC_BYTES + (size_t)2104*(NODES/nc) > ws_size) nc <<= 1;
  const int CB = B_/nc, CN = CB*N0_;
  int cbShift = 0; while ((1 << cbShift) < CB) cbShift++;
  const int cbMask = CB - 1;

  char* wsb = (char*)d_ws; size_t off = 0;
  auto alloc = [&](size_t nbytes)->void*{
    void* p = wsb + off; off = (off + nbytes + 255) & ~(size_t)255; return p;
  };
  int*   zbase  = (int*)  alloc(20080*sizeof(int));
  float* gsum   = (float*)zbase;
  float* gsq    = gsum + 40;
  int*   counts = zbase + 80;
  int*   cursor = counts + 10000;
  float* sA     = (float*)alloc(40*sizeof(float));
  float* sB     = (float*)alloc(40*sizeof(float));
  int*   offs   = (int*)  alloc(10001*sizeof(int));
  int*   srcl   = (int*)  alloc((size_t)NE_*sizeof(int));
  u16*   W1T    = (u16*)  alloc((size_t)272*160*2);
  u16*   W2T    = (u16*)  alloc((size_t)144*288*2);
  u16*   WoT    = (u16*)  alloc((size_t)144*320*2);
  u16*   feat   = (u16*)  alloc((size_t)CN*160*2);
  u16*   h1     = (u16*)  alloc((size_t)CN*288*2);
  u16*   g1     = (u16*)  alloc((size_t)CN*288*2);
  u16*   h2     = (u16*)  alloc((size_t)CN*144*2);
  u16*   g2l    = (u16*)  alloc((size_t)CN*160*2);
  float* asrc1  = (float*)alloc((size_t)CN*2*sizeof(float));
  float* adst1  = (float*)alloc((size_t)CN*2*sizeof(float));
  float* asrc2  = (float*)alloc((size_t)CN*sizeof(float));
  float* adst2  = (float*)alloc((size_t)CN*sizeof(float));
  u16*   res    = h1;

  k_zero<<<79,256,0,stream>>>(zbase, 20080);

  k_bn_stats<<<313,256,0,stream>>>(x, wl1,wl2,wp1,wp2,wg, gsum, gsq);
  k_bn_fin  <<<1,64,0,stream>>>(gsum, gsq, sA, sB, gl1,gl2,gp1,gp2,gg, bel1,bel2,bep1,bep2,beg);

  k_count  <<<665,256,0,stream>>>(ei, counts);
  k_scan   <<<1,1024,0,stream>>>(counts, offs);
  k_scatter<<<665,256,0,stream>>>(ei, offs, cursor, srcl);

  k_wt<<<171,256,0,stream>>>(W1T, W1, 272, 160, 272, 136, 0);
  k_wt<<<162,256,0,stream>>>(W2T, W2, 144, 288, 136, 272, 0);
  k_wt<<<180,256,0,stream>>>(WoT, Wo, 144, 320, 136, 0,   1);

  const int gx = (CN + 255)/256;
  const int aggB = 2500*CB;
  for (int c = 0; c < nc; c++){
    const int base = c*CN;

    k_feat<<<gx,256,0,stream>>>(x, wl1,wl2,wp1,wp2,wg, sA, sB, feat, base, CN);

    k_mfma<5,0,9,0><<<gx,256,0,stream>>>(feat,160, (const u16*)0,0, W1T,160, h1,288,   0, (const float*)0, CN);
    k_mfma<5,0,8,0><<<gx,256,0,stream>>>(feat,160, (const u16*)0,0, W1T,160, h1,288, 144, (const float*)0, CN);
    k_attn<2,136>  <<<CN/4,256,0,stream>>>(h1,288, as1, ad1, asrc1, adst1, CN);
    k_agg<2,272,0> <<<aggB,256,0,stream>>>(h1,288, asrc1, adst1, offs, srcl, bb1, g1,288, cbMask, cbShift);

    k_mfma<9,0,9,0><<<gx,256,0,stream>>>(g1,288, (const u16*)0,0, W2T,288, h2,144, 0, (const float*)0, CN);
    k_attn<1,136>  <<<CN/4,256,0,stream>>>(h2,144, as2, ad2, asrc2, adst2, CN);
    k_agg<1,136,1> <<<aggB,256,0,stream>>>(h2,144, asrc2, adst2, offs, srcl, bb2, g2l,160, cbMask, cbShift);

    k_mfma<5,5,9,1><<<gx,256,0,stream>>>(g2l,160, feat,160, WoT,320, res,144, 0, bo, CN);
    k_head2<<<CN/4,256,0,stream>>>(res,144, Wo2, bo2, (float*)d_out + base, CN);
  }
}